// Round 11
// baseline (321.795 us; speedup 1.0000x reference)
//
#include <hip/hip_runtime.h>
#include <hip/hip_bf16.h>

typedef unsigned short u16;

#define B_    4
#define T_    4096
#define C_    512
#define H_    8
#define D_    64
#define WIN_  15
#define PAD_  7
#define M_    (B_*T_)      // 16384 rows
#define NQKV  1536
#define KDIM  512

typedef __bf16 bf16x8 __attribute__((ext_vector_type(8)));
typedef float  f32x4  __attribute__((ext_vector_type(4)));

__device__ __forceinline__ u16 f2bf(float f) {
    union { float f; unsigned int i; } c; c.f = f;
    unsigned int lsb = (c.i >> 16) & 1u;
    c.i += 0x7fffu + lsb;                 // round-to-nearest-even
    return (u16)(c.i >> 16);
}
__device__ __forceinline__ float bf2f(u16 u) {
    union { unsigned int i; float f; } c; c.i = ((unsigned int)u) << 16; return c.f;
}

// Swizzled LDS chunk offset for BK=64 tiles (u16 units). Chunk = 16B.
// Row = 64 elems = 8 chunks; slot = sub ^ (row&7).
// Staging (8 consecutive lanes share a row-group): classes sub^(row&7)
// cover all 8 -> conflict-free. Frag reads (16 lanes, consecutive rows,
// fixed sub): classes (row&7)^sub cover all 8 twice -> 2-way = free [m136].
__device__ __forceinline__ int swz64(int row, int sub) {
    return (row * 8 + (sub ^ (row & 7))) * 8;
}

// ---------------------------------------------------------------------------
// Pack fp32 weights -> bf16 transposed Wt[n][k].
// Wt_qkv rows: [0,512)=Wq cols, [512,1024)=Wkv k-part, [1024,1536)=Wkv v-part.
// ---------------------------------------------------------------------------
__global__ void pack_weights(const float* __restrict__ Wq, const float* __restrict__ Wkv,
                             const float* __restrict__ Wp,
                             u16* __restrict__ Wt_qkv, u16* __restrict__ Wpt)
{
    int idx = blockIdx.x * blockDim.x + threadIdx.x;   // 0 .. 1536*512-1
    int n = idx >> 9;
    int k = idx & 511;
    float w = (n < 512) ? Wq[k * 512 + n] : Wkv[k * 1024 + (n - 512)];
    Wt_qkv[idx] = f2bf(w);
    if (idx < 512 * 512) Wpt[idx] = f2bf(Wp[k * 512 + n]);
}

// ---------------------------------------------------------------------------
// xm = bf16( x_fp32 * mask[row] ) — one-time pass so GEMM1 never re-converts
// (the fused version converted every A element 12x, once per column block).
// ---------------------------------------------------------------------------
__global__ void apply_mask(const float* __restrict__ x, const float* __restrict__ mask,
                           u16* __restrict__ xm)
{
    int idx = blockIdx.x * blockDim.x + threadIdx.x;   // one per 8 elems
    int e0 = idx * 8;
    float mval = mask[e0 >> 9];
    float4 a = *(const float4*)(x + e0);
    float4 b = *(const float4*)(x + e0 + 4);
    union { uint4 u; u16 s[8]; } o;
    o.s[0] = f2bf(a.x * mval); o.s[1] = f2bf(a.y * mval);
    o.s[2] = f2bf(a.z * mval); o.s[3] = f2bf(a.w * mval);
    o.s[4] = f2bf(b.x * mval); o.s[5] = f2bf(b.y * mval);
    o.s[6] = f2bf(b.z * mval); o.s[7] = f2bf(b.w * mval);
    *(uint4*)(xm + e0) = o.u;
}

// ---------------------------------------------------------------------------
// 128x128 tile MFMA GEMM, C = A(MxK bf16, stride lda) * Bt(NxK)^T + bias.
// BK=64, register-prefetch pipeline: chunks for iter k+1 are loaded into
// VGPRs while iter k computes, so the vmcnt wait lands at next iter's
// ds_write — hidden under compute + both barriers (R9 showed the plain
// 2-barrier loop exposes ~900 cyc HBM latency every iteration).
// USE_MASK: epilogue multiplies by amask[row]. OUT_F32: fp32 C, else bf16.
// MFMA called as mfma(b, a, acc): lane&15 -> C row, quad*4+reg -> C col;
// each lane owns 4 consecutive C columns -> register-direct vector stores.
// ---------------------------------------------------------------------------
template<bool USE_MASK, bool OUT_F32>
__global__ __launch_bounds__(256, 3) void gemm_bt_128(
    const u16* __restrict__ A, int lda,
    const float* __restrict__ amask,  // M fp32
    const u16* __restrict__ Bt,       // N x K row-major bf16 (pre-transposed)
    const float* __restrict__ bias0, const float* __restrict__ bias1,
    void* __restrict__ Cc,            // M x N row-major
    int K, int N)
{
    __shared__ __align__(16) u16 As[128 * 64];   // 16 KB, swizzled
    __shared__ __align__(16) u16 Bs[128 * 64];   // 16 KB, swizzled

    const int tid  = threadIdx.x;
    const int wave = tid >> 6;
    const int lane = tid & 63;
    const int row0 = blockIdx.x * 128;
    const int col0 = blockIdx.y * 128;
    const int wm = (wave >> 1) * 64;   // wave's row offset in tile
    const int wn = (wave & 1) * 64;    // wave's col offset in tile

    f32x4 acc[4][4] = {};              // [ci][ri]

    const int quad = lane >> 4;
    const int l16  = lane & 15;

    // per-thread staging chunks: c = tid + 256*i -> row=c>>3, sub=c&7
    int srow[4], ssub[4];
    #pragma unroll
    for (int i = 0; i < 4; i++) { int c = tid + 256 * i; srow[i] = c >> 3; ssub[i] = c & 7; }

    uint4 pa[4], pb[4];
    #pragma unroll
    for (int i = 0; i < 4; i++) {
        pa[i] = *(const uint4*)(A  + (size_t)(row0 + srow[i]) * lda + ssub[i] * 8);
        pb[i] = *(const uint4*)(Bt + (size_t)(col0 + srow[i]) * K   + ssub[i] * 8);
    }

    for (int k0 = 0; k0 < K; k0 += 64) {
        __syncthreads();   // all waves done reading LDS from previous iter
        #pragma unroll
        for (int i = 0; i < 4; i++) {
            *(uint4*)&As[swz64(srow[i], ssub[i])] = pa[i];
            *(uint4*)&Bs[swz64(srow[i], ssub[i])] = pb[i];
        }
        __syncthreads();   // staging visible to all waves

        if (k0 + 64 < K) {     // prefetch next K-chunk into registers
            #pragma unroll
            for (int i = 0; i < 4; i++) {
                pa[i] = *(const uint4*)(A  + (size_t)(row0 + srow[i]) * lda + k0 + 64 + ssub[i] * 8);
                pb[i] = *(const uint4*)(Bt + (size_t)(col0 + srow[i]) * K   + k0 + 64 + ssub[i] * 8);
            }
        }

        #pragma unroll
        for (int hf = 0; hf < 2; hf++) {
            bf16x8 a[4], b[4];
            #pragma unroll
            for (int i = 0; i < 4; i++) {
                a[i] = *(const bf16x8*)&As[swz64(wm + i * 16 + l16, hf * 4 + quad)];
                b[i] = *(const bf16x8*)&Bs[swz64(wn + i * 16 + l16, hf * 4 + quad)];
            }
            #pragma unroll
            for (int ci = 0; ci < 4; ci++)
                #pragma unroll
                for (int ri = 0; ri < 4; ri++)
                    acc[ci][ri] = __builtin_amdgcn_mfma_f32_16x16x32_bf16(
                        b[ci], a[ri], acc[ci][ri], 0, 0, 0);
        }
    }

    // ---- epilogue: register-direct vectorized stores (R9, conflicts=0) ----
    #pragma unroll
    for (int ri = 0; ri < 4; ri++) {
        const int row = row0 + wm + ri * 16 + l16;
        float mval = 1.f;
        if (USE_MASK) mval = amask[row];
        #pragma unroll
        for (int ci = 0; ci < 4; ci++) {
            const int colb = col0 + wn + ci * 16 + quad * 4;
            float4 bv = (colb < 512) ? *(const float4*)(bias0 + colb)
                                     : *(const float4*)(bias1 + colb - 512);
            f32x4 v = acc[ci][ri];
            float v0 = v[0] + bv.x, v1 = v[1] + bv.y,
                  v2 = v[2] + bv.z, v3 = v[3] + bv.w;
            if (USE_MASK) { v0 *= mval; v1 *= mval; v2 *= mval; v3 *= mval; }
            if (OUT_F32) {
                float4 o = make_float4(v0, v1, v2, v3);
                *(float4*)((float*)Cc + (size_t)row * N + colb) = o;
            } else {
                union { uint2 u; u16 s[4]; } o;
                o.s[0] = f2bf(v0); o.s[1] = f2bf(v1);
                o.s[2] = f2bf(v2); o.s[3] = f2bf(v3);
                *(uint2*)((u16*)Cc + (size_t)row * N + colb) = o.u;
            }
        }
    }
}

// ---------------------------------------------------------------------------
// Windowed attention: thread-per-(t,h), k/v staged in LDS [jchunk][row].
// Rows outside [0,T) get the bias row. Output in place over the q slot.
// ---------------------------------------------------------------------------
__global__ __launch_bounds__(256) void attn_win2(u16* __restrict__ qkv,
                                                 const float* __restrict__ bkv)
{
    __shared__ uint4 klds[8 * 270];   // [j][row], row = t0-7+row
    __shared__ uint4 vlds[8 * 270];

    const int tid = threadIdx.x;
    const int bid = blockIdx.x;
    const int h  = bid & 7;
    const int b  = (bid >> 3) & 3;
    const int tb = bid >> 5;          // [0,16)
    const int t0 = tb * 256;

    #pragma unroll
    for (int i = 0; i < 9; i++) {
        int idx = i * 256 + tid;
        if (idx < 2160) {
            int row = idx % 270;
            int j   = idx / 270;
            int tt  = t0 - 7 + row;
            uint4 kc, vc;
            if ((unsigned)tt < (unsigned)T_) {
                const u16* g = qkv + ((size_t)b * T_ + tt) * NQKV + 512 + h * 64 + j * 8;
                kc = *(const uint4*)g;
                vc = *(const uint4*)(g + 512);
            } else {
                union { uint4 u; u16 s[8]; } pk, pv;
                #pragma unroll
                for (int e = 0; e < 8; e++) {
                    pk.s[e] = f2bf(bkv[h * 64 + j * 8 + e]);
                    pv.s[e] = f2bf(bkv[512 + h * 64 + j * 8 + e]);
                }
                kc = pk.u; vc = pv.u;
            }
            klds[j * 270 + row] = kc;
            vlds[j * 270 + row] = vc;
        }
    }
    __syncthreads();

    const size_t m = (size_t)b * T_ + t0 + tid;
    u16* qrow = qkv + m * NQKV + h * 64;

    float qf[64];
    #pragma unroll
    for (int j = 0; j < 8; j++) {
        union { uint4 u; u16 s[8]; } t;
        t.u = *(const uint4*)(qrow + j * 8);
        #pragma unroll
        for (int e = 0; e < 8; e++) qf[j * 8 + e] = bf2f(t.s[e]);
    }

    const float scale = 0.042313283f;   // ln(15)/64
    float s[WIN_];
    #pragma unroll
    for (int w = 0; w < WIN_; w++) {
        float acc = 0.f;
        #pragma unroll
        for (int j = 0; j < 8; j++) {
            union { uint4 u; u16 e[8]; } kc;
            kc.u = klds[j * 270 + tid + w];
            #pragma unroll
            for (int e2 = 0; e2 < 8; e2++)
                acc += qf[j * 8 + e2] * bf2f(kc.e[e2]);
        }
        s[w] = acc * scale;
    }

    float mx = s[0];
    #pragma unroll
    for (int w = 1; w < WIN_; w++) mx = fmaxf(mx, s[w]);
    float sum = 0.f;
    #pragma unroll
    for (int w = 0; w < WIN_; w++) { s[w] = __expf(s[w] - mx); sum += s[w]; }
    const float inv = 1.0f / sum;
    #pragma unroll
    for (int w = 0; w < WIN_; w++) s[w] *= inv;

    #pragma unroll
    for (int j = 0; j < 8; j++) {
        float o[8] = {};
        #pragma unroll
        for (int w = 0; w < WIN_; w++) {
            union { uint4 u; u16 e[8]; } vc;
            vc.u = vlds[j * 270 + tid + w];
            #pragma unroll
            for (int e2 = 0; e2 < 8; e2++) o[e2] += s[w] * bf2f(vc.e[e2]);
        }
        union { uint4 u; u16 e[8]; } oc;
        #pragma unroll
        for (int e2 = 0; e2 < 8; e2++) oc.e[e2] = f2bf(o[e2]);
        *(uint4*)(qrow + j * 8) = oc.u;
    }
}

// ---------------------------------------------------------------------------
// Workspace: 66 MiB total (R3 ran 84 MiB deterministically -> safe).
//   [0, 1.5Mi)    Wt_qkv (1536x512 bf16)
//   [1.5Mi, 2Mi)  Wpt    (512x512 bf16)
//   [2Mi, 18Mi)   xm     (16384x512 bf16)
//   [18Mi, 66Mi)  qkv    (16384x1536 bf16); q section reused for attn output
// ---------------------------------------------------------------------------
extern "C" void kernel_launch(void* const* d_in, const int* in_sizes, int n_in,
                              void* d_out, int out_size, void* d_ws, size_t ws_size,
                              hipStream_t stream)
{
    const float* x    = (const float*)d_in[0];
    const float* mask = (const float*)d_in[1];
    const float* Wq   = (const float*)d_in[2];
    const float* bq   = (const float*)d_in[3];
    const float* Wkv  = (const float*)d_in[4];
    const float* bkv  = (const float*)d_in[5];
    const float* Wp   = (const float*)d_in[6];
    const float* bp   = (const float*)d_in[7];
    float* out = (float*)d_out;

    char* ws = (char*)d_ws;
    u16* Wt_qkv = (u16*)(ws);
    u16* Wpt    = (u16*)(ws + (size_t)(1536 * 1024));
    u16* xm     = (u16*)(ws + (size_t)(2048 * 1024));
    u16* qkv    = (u16*)(ws + (size_t)(18 * 1024 * 1024));

    pack_weights<<<NQKV * KDIM / 256, 256, 0, stream>>>(Wq, Wkv, Wp, Wt_qkv, Wpt);

    apply_mask<<<(M_ * C_) / (8 * 256), 256, 0, stream>>>(x, mask, xm);

    dim3 g1(M_ / 128, NQKV / 128);
    gemm_bt_128<false, false><<<g1, 256, 0, stream>>>(
        xm, KDIM, mask, Wt_qkv, bq, bkv, qkv, KDIM, NQKV);

    attn_win2<<<(T_ / 256) * B_ * H_, 256, 0, stream>>>(qkv, bkv);

    dim3 g2(M_ / 128, C_ / 128);
    gemm_bt_128<true, true><<<g2, 256, 0, stream>>>(
        qkv, NQKV, mask, Wpt, bp, nullptr, out, KDIM, C_);
}

// Round 12
// 193.510 us; speedup vs baseline: 1.6629x; 1.6629x over previous
//
#include <hip/hip_runtime.h>
#include <hip/hip_bf16.h>

typedef unsigned short u16;

#define B_    4
#define T_    4096
#define C_    512
#define H_    8
#define D_    64
#define WIN_  15
#define PAD_  7
#define M_    (B_*T_)      // 16384 rows
#define NQKV  1536
#define KDIM  512

typedef __bf16 bf16x8 __attribute__((ext_vector_type(8)));
typedef float  f32x4  __attribute__((ext_vector_type(4)));

__device__ __forceinline__ u16 f2bf(float f) {
    union { float f; unsigned int i; } c; c.f = f;
    unsigned int lsb = (c.i >> 16) & 1u;
    c.i += 0x7fffu + lsb;                 // round-to-nearest-even
    return (u16)(c.i >> 16);
}
__device__ __forceinline__ float bf2f(u16 u) {
    union { unsigned int i; float f; } c; c.i = ((unsigned int)u) << 16; return c.f;
}

// Swizzled LDS chunk offset, BK=32 (u16 units). Chunk = 16B = 8 bf16.
// slot = sub ^ ((row>>1)&3): staging writes and fragment reads both
// conflict-free [R9: SQ_LDS_BANK_CONFLICT 3.1M -> 0].
__device__ __forceinline__ int swz(int row, int sub) {
    return (row * 4 + (sub ^ ((row >> 1) & 3))) * 8;
}

// ---------------------------------------------------------------------------
// Pack fp32 weights -> bf16 transposed Wt[n][k].
// Wt_qkv rows: [0,512)=Wq cols, [512,1024)=Wkv k-part, [1024,1536)=Wkv v-part.
// ---------------------------------------------------------------------------
__global__ void pack_weights(const float* __restrict__ Wq, const float* __restrict__ Wkv,
                             const float* __restrict__ Wp,
                             u16* __restrict__ Wt_qkv, u16* __restrict__ Wpt)
{
    int idx = blockIdx.x * blockDim.x + threadIdx.x;   // 0 .. 1536*512-1
    int n = idx >> 9;
    int k = idx & 511;
    float w = (n < 512) ? Wq[k * 512 + n] : Wkv[k * 1024 + (n - 512)];
    Wt_qkv[idx] = f2bf(w);
    if (idx < 512 * 512) Wpt[idx] = f2bf(Wp[k * 512 + n]);
}

// ---------------------------------------------------------------------------
// xm = bf16( x_fp32 * mask[row] ) — one-time pass so GEMM1 never re-converts.
// ---------------------------------------------------------------------------
__global__ void apply_mask(const float* __restrict__ x, const float* __restrict__ mask,
                           u16* __restrict__ xm)
{
    int idx = blockIdx.x * blockDim.x + threadIdx.x;   // one per 8 elems
    int e0 = idx * 8;
    float mval = mask[e0 >> 9];
    float4 a = *(const float4*)(x + e0);
    float4 b = *(const float4*)(x + e0 + 4);
    union { uint4 u; u16 s[8]; } o;
    o.s[0] = f2bf(a.x * mval); o.s[1] = f2bf(a.y * mval);
    o.s[2] = f2bf(a.z * mval); o.s[3] = f2bf(a.w * mval);
    o.s[4] = f2bf(b.x * mval); o.s[5] = f2bf(b.y * mval);
    o.s[6] = f2bf(b.z * mval); o.s[7] = f2bf(b.w * mval);
    *(uint4*)(xm + e0) = o.u;
}

// ---------------------------------------------------------------------------
// 128x128 tile MFMA GEMM, C = A(MxK bf16, stride lda) * Bt(NxK)^T + bias.
// BK=32, one-stage register prefetch: iter k's compute covers iter k+1's
// global loads, so the vmcnt drain lands at the next ds_write instead of
// being fully exposed (R9: ~900 cyc exposed per iter).
// NO __launch_bounds__ min-waves: R11 showed forcing 3 waves/EU with 64 acc
// VGPRs (unified AGPR file) causes catastrophic scratch spill (415 MB writes).
// USE_MASK: epilogue multiplies by amask[row]. OUT_F32: fp32 C, else bf16.
// MFMA as mfma(b, a, acc): lane&15 -> C row, quad*4+reg -> C col; each lane
// owns 4 consecutive C columns -> register-direct vector stores [R9].
// ---------------------------------------------------------------------------
template<bool USE_MASK, bool OUT_F32>
__global__ __launch_bounds__(256) void gemm_bt_128(
    const u16* __restrict__ A, int lda,
    const float* __restrict__ amask,  // M fp32
    const u16* __restrict__ Bt,       // N x K row-major bf16 (pre-transposed)
    const float* __restrict__ bias0, const float* __restrict__ bias1,
    void* __restrict__ Cc,            // M x N row-major
    int K, int N)
{
    __shared__ __align__(16) u16 As[128 * 32];   // 8 KB, swizzled
    __shared__ __align__(16) u16 Bs[128 * 32];   // 8 KB, swizzled

    const int tid  = threadIdx.x;
    const int wave = tid >> 6;
    const int lane = tid & 63;
    const int row0 = blockIdx.x * 128;
    const int col0 = blockIdx.y * 128;
    const int wm = (wave >> 1) * 64;   // wave's row offset in tile
    const int wn = (wave & 1) * 64;    // wave's col offset in tile

    f32x4 acc[4][4] = {};              // [ci][ri]

    const int quad = lane >> 4;
    const int l16  = lane & 15;

    // staging chunks: c in [0,512), row = c>>2, sub = c&3
    const int c0 = tid, c1 = tid + 256;
    const int r0l = c0 >> 2, s0 = c0 & 3;
    const int r1l = c1 >> 2, s1 = c1 & 3;
    const u16* A0p = A  + (size_t)(row0 + r0l) * lda + s0 * 8;
    const u16* A1p = A  + (size_t)(row0 + r1l) * lda + s1 * 8;
    const u16* B0p = Bt + (size_t)(col0 + r0l) * K   + s0 * 8;
    const u16* B1p = Bt + (size_t)(col0 + r1l) * K   + s1 * 8;

    // preload k=0
    uint4 ra0 = *(const uint4*)(A0p);
    uint4 ra1 = *(const uint4*)(A1p);
    uint4 rb0 = *(const uint4*)(B0p);
    uint4 rb1 = *(const uint4*)(B1p);

    for (int k0 = 0; k0 < K; k0 += 32) {
        __syncthreads();   // all waves done reading LDS from previous iter
        *(uint4*)&As[swz(r0l, s0)] = ra0;
        *(uint4*)&As[swz(r1l, s1)] = ra1;
        *(uint4*)&Bs[swz(r0l, s0)] = rb0;
        *(uint4*)&Bs[swz(r1l, s1)] = rb1;
        __syncthreads();   // staging visible to all waves

        if (k0 + 32 < K) {             // issue next chunk; wait lands at
            ra0 = *(const uint4*)(A0p + k0 + 32);   // next iter's ds_write,
            ra1 = *(const uint4*)(A1p + k0 + 32);   // covered by compute
            rb0 = *(const uint4*)(B0p + k0 + 32);
            rb1 = *(const uint4*)(B1p + k0 + 32);
        }

        bf16x8 a[4], b[4];
        #pragma unroll
        for (int i = 0; i < 4; i++) {
            a[i] = *(const bf16x8*)&As[swz(wm + i * 16 + l16, quad)];
            b[i] = *(const bf16x8*)&Bs[swz(wn + i * 16 + l16, quad)];
        }
        #pragma unroll
        for (int ci = 0; ci < 4; ci++)
            #pragma unroll
            for (int ri = 0; ri < 4; ri++)
                acc[ci][ri] = __builtin_amdgcn_mfma_f32_16x16x32_bf16(
                    b[ci], a[ri], acc[ci][ri], 0, 0, 0);
    }

    // ---- epilogue: register-direct vectorized stores (R9, conflicts=0) ----
    #pragma unroll
    for (int ri = 0; ri < 4; ri++) {
        const int row = row0 + wm + ri * 16 + l16;
        float mval = 1.f;
        if (USE_MASK) mval = amask[row];
        #pragma unroll
        for (int ci = 0; ci < 4; ci++) {
            const int colb = col0 + wn + ci * 16 + quad * 4;
            float4 bv = (colb < 512) ? *(const float4*)(bias0 + colb)
                                     : *(const float4*)(bias1 + colb - 512);
            f32x4 v = acc[ci][ri];
            float v0 = v[0] + bv.x, v1 = v[1] + bv.y,
                  v2 = v[2] + bv.z, v3 = v[3] + bv.w;
            if (USE_MASK) { v0 *= mval; v1 *= mval; v2 *= mval; v3 *= mval; }
            if (OUT_F32) {
                float4 o = make_float4(v0, v1, v2, v3);
                *(float4*)((float*)Cc + (size_t)row * N + colb) = o;
            } else {
                union { uint2 u; u16 s[4]; } o;
                o.s[0] = f2bf(v0); o.s[1] = f2bf(v1);
                o.s[2] = f2bf(v2); o.s[3] = f2bf(v3);
                *(uint2*)((u16*)Cc + (size_t)row * N + colb) = o.u;
            }
        }
    }
}

// ---------------------------------------------------------------------------
// Windowed attention: thread-per-(t,h), k/v staged in LDS [jchunk][row].
// Rows outside [0,T) get the bias row. Output in place over the q slot.
// ---------------------------------------------------------------------------
__global__ __launch_bounds__(256) void attn_win2(u16* __restrict__ qkv,
                                                 const float* __restrict__ bkv)
{
    __shared__ uint4 klds[8 * 270];   // [j][row], row = t0-7+row
    __shared__ uint4 vlds[8 * 270];

    const int tid = threadIdx.x;
    const int bid = blockIdx.x;
    const int h  = bid & 7;
    const int b  = (bid >> 3) & 3;
    const int tb = bid >> 5;          // [0,16)
    const int t0 = tb * 256;

    #pragma unroll
    for (int i = 0; i < 9; i++) {
        int idx = i * 256 + tid;
        if (idx < 2160) {
            int row = idx % 270;
            int j   = idx / 270;
            int tt  = t0 - 7 + row;
            uint4 kc, vc;
            if ((unsigned)tt < (unsigned)T_) {
                const u16* g = qkv + ((size_t)b * T_ + tt) * NQKV + 512 + h * 64 + j * 8;
                kc = *(const uint4*)g;
                vc = *(const uint4*)(g + 512);
            } else {
                union { uint4 u; u16 s[8]; } pk, pv;
                #pragma unroll
                for (int e = 0; e < 8; e++) {
                    pk.s[e] = f2bf(bkv[h * 64 + j * 8 + e]);
                    pv.s[e] = f2bf(bkv[512 + h * 64 + j * 8 + e]);
                }
                kc = pk.u; vc = pv.u;
            }
            klds[j * 270 + row] = kc;
            vlds[j * 270 + row] = vc;
        }
    }
    __syncthreads();

    const size_t m = (size_t)b * T_ + t0 + tid;
    u16* qrow = qkv + m * NQKV + h * 64;

    float qf[64];
    #pragma unroll
    for (int j = 0; j < 8; j++) {
        union { uint4 u; u16 s[8]; } t;
        t.u = *(const uint4*)(qrow + j * 8);
        #pragma unroll
        for (int e = 0; e < 8; e++) qf[j * 8 + e] = bf2f(t.s[e]);
    }

    const float scale = 0.042313283f;   // ln(15)/64
    float s[WIN_];
    #pragma unroll
    for (int w = 0; w < WIN_; w++) {
        float acc = 0.f;
        #pragma unroll
        for (int j = 0; j < 8; j++) {
            union { uint4 u; u16 e[8]; } kc;
            kc.u = klds[j * 270 + tid + w];
            #pragma unroll
            for (int e2 = 0; e2 < 8; e2++)
                acc += qf[j * 8 + e2] * bf2f(kc.e[e2]);
        }
        s[w] = acc * scale;
    }

    float mx = s[0];
    #pragma unroll
    for (int w = 1; w < WIN_; w++) mx = fmaxf(mx, s[w]);
    float sum = 0.f;
    #pragma unroll
    for (int w = 0; w < WIN_; w++) { s[w] = __expf(s[w] - mx); sum += s[w]; }
    const float inv = 1.0f / sum;
    #pragma unroll
    for (int w = 0; w < WIN_; w++) s[w] *= inv;

    #pragma unroll
    for (int j = 0; j < 8; j++) {
        float o[8] = {};
        #pragma unroll
        for (int w = 0; w < WIN_; w++) {
            union { uint4 u; u16 e[8]; } vc;
            vc.u = vlds[j * 270 + tid + w];
            #pragma unroll
            for (int e2 = 0; e2 < 8; e2++) o[e2] += s[w] * bf2f(vc.e[e2]);
        }
        union { uint4 u; u16 e[8]; } oc;
        #pragma unroll
        for (int e2 = 0; e2 < 8; e2++) oc.e[e2] = f2bf(o[e2]);
        *(uint4*)(qrow + j * 8) = oc.u;
    }
}

// ---------------------------------------------------------------------------
// Workspace: 66 MiB total.
//   [0, 1.5Mi)    Wt_qkv (1536x512 bf16)
//   [1.5Mi, 2Mi)  Wpt    (512x512 bf16)
//   [2Mi, 18Mi)   xm     (16384x512 bf16)
//   [18Mi, 66Mi)  qkv    (16384x1536 bf16); q section reused for attn output
// ---------------------------------------------------------------------------
extern "C" void kernel_launch(void* const* d_in, const int* in_sizes, int n_in,
                              void* d_out, int out_size, void* d_ws, size_t ws_size,
                              hipStream_t stream)
{
    const float* x    = (const float*)d_in[0];
    const float* mask = (const float*)d_in[1];
    const float* Wq   = (const float*)d_in[2];
    const float* bq   = (const float*)d_in[3];
    const float* Wkv  = (const float*)d_in[4];
    const float* bkv  = (const float*)d_in[5];
    const float* Wp   = (const float*)d_in[6];
    const float* bp   = (const float*)d_in[7];
    float* out = (float*)d_out;

    char* ws = (char*)d_ws;
    u16* Wt_qkv = (u16*)(ws);
    u16* Wpt    = (u16*)(ws + (size_t)(1536 * 1024));
    u16* xm     = (u16*)(ws + (size_t)(2048 * 1024));
    u16* qkv    = (u16*)(ws + (size_t)(18 * 1024 * 1024));

    pack_weights<<<NQKV * KDIM / 256, 256, 0, stream>>>(Wq, Wkv, Wp, Wt_qkv, Wpt);

    apply_mask<<<(M_ * C_) / (8 * 256), 256, 0, stream>>>(x, mask, xm);

    dim3 g1(M_ / 128, NQKV / 128);
    gemm_bt_128<false, false><<<g1, 256, 0, stream>>>(
        xm, KDIM, mask, Wt_qkv, bq, bkv, qkv, KDIM, NQKV);

    attn_win2<<<(T_ / 256) * B_ * H_, 256, 0, stream>>>(qkv, bkv);

    dim3 g2(M_ / 128, C_ / 128);
    gemm_bt_128<true, true><<<g2, 256, 0, stream>>>(
        qkv, NQKV, mask, Wpt, bp, nullptr, out, KDIM, C_);
}